// Round 9
// baseline (3091.468 us; speedup 1.0000x reference)
//
#include <hip/hip_runtime.h>

#define BATCH 65536
#define RT 64              // rows per block
#define NBLK (BATCH/RT)    // 1024
#define NTHR 512           // 8 waves; wave w owns all 64 rows x (units w*32..w*32+31) x 4 gates
#define HS 264             // bf16 elems per LDS h row (256 + 8 pad)

typedef __bf16 v8bf __attribute__((ext_vector_type(8)));
typedef float  v4f  __attribute__((ext_vector_type(4)));
#define MFMA __builtin_amdgcn_mfma_f32_16x16x32_bf16

// ws layout, bf16-element offsets
// B packs: [kc 8][w 8][nt 8][lane 64][j 8]; nt = gate*2 + ub; col g = gate*256 + w*32 + ub*16 + (lane&15)
#define WHH_ELE 0
#define WZ_ELE  262144
#define EXT_ELE 524288     // [w 8][nt 8][lane 64][j 8], K=32 one-hot table (p=(lane>>4)*8+j)
#define WT_ELE  557056     // [kc 8][lane 64][j 8], N=16 (4 valid)
#define WM_ELE  561152     // [kc 8][lane 64][j 8], N=16 (11 valid)
#define WS_ELE_TOTAL 565248

// d_out layout (float offsets): log_p | t_actions | m_actions | t_ent | m_ent
#define OUT_LP 0
#define OUT_TA 65536
#define OUT_MA 589824
#define OUT_TENT 1114112
#define OUT_MENT 1114113

// v_rcp_f32 (~1 ulp) instead of IEEE div microcode
__device__ __forceinline__ float rcpf(float x){ return __builtin_amdgcn_rcpf(x); }
__device__ __forceinline__ float sigf(float x){ return rcpf(1.0f+__expf(-x)); }
__device__ __forceinline__ float tanhf_(float x){
  x = fminf(fmaxf(x, -15.0f), 15.0f);
  float e = __expf(2.0f*x);
  return 1.0f - 2.0f*rcpf(e+1.0f);   // == (e-1)/(e+1)
}
__device__ __forceinline__ unsigned short f32_to_bf16(float x){
  unsigned u = __float_as_uint(x);
  unsigned r = (u + 0x7fffu + ((u>>16)&1u)) >> 16;   // RNE
  return (unsigned short)r;
}

__global__ void precompute_kernel(const float* __restrict__ W_ih, const float* __restrict__ W_hh,
                                  const float* __restrict__ b_ih, const float* __restrict__ b_hh,
                                  const float* __restrict__ action_emb, const float* __restrict__ branch_emb,
                                  const float* __restrict__ actionid_emb,
                                  const float* __restrict__ W_t, const float* __restrict__ W_m,
                                  unsigned short* __restrict__ wsp, float* __restrict__ d_out) {
  int tid = blockIdx.x*256 + threadIdx.x;
  if (tid == 0) { d_out[OUT_TENT] = 0.f; d_out[OUT_MENT] = 0.f; }
  if (tid >= WS_ELE_TOTAL) return;
  float val = 0.f;
  if (tid < 524288) {                        // WHH / WZ packs
    int i = (tid < 262144) ? tid : tid - 262144;
    int j = i & 7, lane = (i>>3)&63, nt = (i>>9)&7, w = (i>>12)&7, kc = (i>>15)&7;
    int k = kc*32 + (lane>>4)*8 + j;
    int g = (nt>>1)*256 + w*32 + (nt&1)*16 + (lane&15);
    val = (tid < 262144) ? W_hh[g*256 + k] : W_ih[g*448 + k];
  } else if (tid < 557056) {                 // EXT one-hot table, K=32
    int i = tid - 524288;
    int j = i & 7, lane = (i>>3)&63, nt = (i>>9)&7, w = (i>>12)&7;
    int p = (lane>>4)*8 + j;
    int g = (nt>>1)*256 + w*32 + (nt&1)*16 + (lane&15);
    if (p < 16) {                            // action_emb[p] @ W_ih[:,384:448].T
      float s = 0.f;
      for (int e=0;e<64;++e) s += action_emb[p*64+e]*W_ih[g*448+384+e];
      val = s;
    } else if (p < 20) {                     // bias + branch + actionid, cidx = 16+2*br+aid
      int q = p-16, br = q>>1, aid = q&1;
      float s = b_ih[g] + b_hh[g];
      for (int e=0;e<64;++e)
        s += branch_emb[br*64+e]*W_ih[g*448+256+e] + actionid_emb[aid*64+e]*W_ih[g*448+320+e];
      val = s;
    }
  } else {                                   // WT / WM packs
    int base = (tid < 561152) ? 557056 : 561152;
    int i = tid - base;
    int j = i & 7, lane = (i>>3)&63, kc = (i>>9)&7;
    int k = kc*32 + (lane>>4)*8 + j;
    int a = lane & 15;
    if (tid < 561152) val = (a < 4)  ? W_t[a*256 + k] : 0.f;
    else              val = (a < 11) ? W_m[a*256 + k] : 0.f;
  }
  wsp[tid] = f32_to_bf16(val);
}

// HALF gemm, kc = KC0..7 (KC0=1 when kc=0 runs from persisted panels). Static UB.
template<int UB, int KC0>
__device__ __forceinline__ void run_gemm_h(v4f acc[4][4], const v8bf* __restrict__ Bw,
                                           const unsigned short* __restrict__ lds,
                                           int col, int quad) {
  #pragma unroll 2
  for (int kc = KC0; kc < 8; ++kc) {
    v8bf A[4];
    #pragma unroll
    for (int mt=0;mt<4;++mt)
      A[mt] = *(const v8bf*)&lds[(mt*16+col)*HS + kc*32 + quad*8];
    #pragma unroll
    for (int g=0;g<4;++g) {
      v8bf B = Bw[kc*4096 + (g*2+UB)*64];
      #pragma unroll
      for (int mt=0;mt<4;++mt)
        acc[mt][g] = MFMA(A[mt], B, acc[mt][g], 0,0,0);
    }
  }
}

// kc=0 of the Whh gemm from PERSISTED register panels (no L2 loads)
template<int UB>
__device__ __forceinline__ void run_kc0(v4f acc[4][4], const v8bf (&b0)[8],
                                        const unsigned short* __restrict__ lds,
                                        int col, int quad) {
  v8bf A[4];
  #pragma unroll
  for (int mt=0;mt<4;++mt)
    A[mt] = *(const v8bf*)&lds[(mt*16+col)*HS + quad*8];
  #pragma unroll
  for (int g=0;g<4;++g)
    #pragma unroll
    for (int mt=0;mt<4;++mt)
      acc[mt][g] = MFMA(A[mt], b0[g*2+UB], acc[mt][g], 0,0,0);
}

// one-hot K=32 chunk from PERSISTED ext panels (no L2 loads; first MFMAs of the
// half start immediately while the kc1-7 Whh loads are in flight)
template<int UB>
__device__ __forceinline__ void run_ext_h(v4f acc[4][4], const v8bf (&ewr)[8],
                                          const int* __restrict__ idx, int cidx,
                                          int col, int quad) {
  #pragma unroll
  for (int mt=0;mt<4;++mt) {
    int p0 = idx[mt*16 + col];
    v8bf oh;
    #pragma unroll
    for (int j=0;j<8;++j) { int k = quad*8+j; oh[j] = (k==p0 || k==cidx) ? (__bf16)1.0f : (__bf16)0.0f; }
    #pragma unroll
    for (int g=0;g<4;++g)
      acc[mt][g] = MFMA(oh, ewr[g*2+UB], acc[mt][g], 0,0,0);
  }
}

// base = z @ Wz^T, one UB half, pack bf16 into bpk (static indices; no persists —
// Bz panels are only read twice per kernel)
template<int UB>
__device__ __forceinline__ void base_half(unsigned (&bpk)[4][8][2], const v8bf* __restrict__ Bz,
                                          const unsigned short* __restrict__ lds,
                                          int col, int quad) {
  v4f acc[4][4];
  #pragma unroll
  for (int mt=0;mt<4;++mt)
    #pragma unroll
    for (int g=0;g<4;++g) acc[mt][g] = (v4f){0.f,0.f,0.f,0.f};
  run_gemm_h<UB,0>(acc, Bz, lds, col, quad);
  #pragma unroll
  for (int mt=0;mt<4;++mt)
    #pragma unroll
    for (int g=0;g<4;++g) {
      bpk[mt][g*2+UB][0] = (unsigned)f32_to_bf16(acc[mt][g][0]) | ((unsigned)f32_to_bf16(acc[mt][g][1])<<16);
      bpk[mt][g*2+UB][1] = (unsigned)f32_to_bf16(acc[mt][g][2]) | ((unsigned)f32_to_bf16(acc[mt][g][3])<<16);
    }
}

// one LSTM half-step: acc init from bpk, ext (persisted), kc0 (persisted), kc1-7 (L2),
// gates, write dst h
template<int UB>
__device__ __forceinline__ void lstm_half(unsigned (&bpk)[4][8][2], float (&c_st)[4][2][4],
                                          const v8bf (&ewr)[8], const v8bf (&bh0)[8],
                                          const v8bf* __restrict__ Bhh,
                                          const int* __restrict__ idx, int cidx,
                                          const unsigned short* __restrict__ src,
                                          unsigned short* __restrict__ dst,
                                          int col, int quad, int wv) {
  v4f acc[4][4];
  #pragma unroll
  for (int mt=0;mt<4;++mt)
    #pragma unroll
    for (int g=0;g<4;++g) {
      unsigned p0 = bpk[mt][g*2+UB][0], p1 = bpk[mt][g*2+UB][1];
      acc[mt][g] = (v4f){ __uint_as_float(p0<<16), __uint_as_float(p0 & 0xffff0000u),
                          __uint_as_float(p1<<16), __uint_as_float(p1 & 0xffff0000u) };
    }
  run_ext_h<UB>(acc, ewr, idx, cidx, col, quad);
  run_kc0<UB>(acc, bh0, src, col, quad);
  run_gemm_h<UB,1>(acc, Bhh, src, col, quad);
  #pragma unroll
  for (int mt=0;mt<4;++mt)
    #pragma unroll
    for (int rg=0;rg<4;++rg) {
      float gi = sigf(acc[mt][0][rg]);
      float gf = sigf(acc[mt][1][rg]);
      float gg = tanhf_(acc[mt][2][rg]);
      float go = sigf(acc[mt][3][rg]);
      float cn = gf*c_st[mt][UB][rg] + gi*gg;
      c_st[mt][UB][rg] = cn;
      dst[(mt*16 + quad*4 + rg)*HS + wv*32 + UB*16 + col] = f32_to_bf16(go*tanhf_(cn));
    }
}

// softmax over 11 m-logits (bias pre-folded into ml_lds). All static indexing.
__device__ __forceinline__ void softmax_m(const float* __restrict__ ml, int t, int ma,
                                          float& lp, float& entM) {
  float mv[11];
  #pragma unroll
  for (int a=0;a<11;++a) mv[a] = ml[t*12+a];
  float mx = mv[0];
  #pragma unroll
  for (int a=1;a<11;++a) mx = fmaxf(mx, mv[a]);
  float se = 0.f;
  #pragma unroll
  for (int a=0;a<11;++a) se += __expf(mv[a]-mx);
  float lse = mx + __logf(se);
  float sel = mv[0];
  #pragma unroll
  for (int a=1;a<11;++a) sel = (ma==a) ? mv[a] : sel;
  lp += sel - lse;
  float e = 0.f;
  #pragma unroll
  for (int a=0;a<11;++a) { float l2 = mv[a]-lse; e -= __expf(l2)*l2; }
  entM += e;
}

// launch_bounds(,2): pin allocator to <=256 regs/wave (2 waves/SIMD). Register
// budget: persist 64 (ewr+bh0) + acc 64 + bpk 64 + c_st 32 + temps ~= 245.
// The ub backedge (unroll-1 + branch dispatch) keeps one acc live at a time.
__global__ __launch_bounds__(NTHR, 2) void decoder_main(
    const float* __restrict__ z1, const float* __restrict__ z2,
    const int* __restrict__ t_act, const int* __restrict__ m_act,
    const float* __restrict__ b_t, const float* __restrict__ b_m,
    const unsigned short* __restrict__ wsp, float* __restrict__ d_out) {
  // LDS: 2x33.8KB h buffers + ~7.3KB small = ~75.0KB. z staged INTO hB at branch head.
  __shared__ __align__(16) unsigned short hA[RT*HS];    // 33.8KB, [row][k] bf16
  __shared__ __align__(16) unsigned short hB[RT*HS];    // 33.8KB (double buffer; z staging at head)
  __shared__ float tl_lds[RT*4];
  __shared__ float ml_lds[RT*12];
  __shared__ int ta_l[4*RT], ma_l[4*RT], pa_l[4*RT], carry_l[RT];

  const int t = threadIdx.x, wv = t>>6, l = t&63, col = l&15, quad = l>>4;
  const int r0 = blockIdx.x * RT;
  const v8bf* Bhh = ((const v8bf*)(wsp + WHH_ELE)) + wv*512 + l;
  const v8bf* Bz  = ((const v8bf*)(wsp + WZ_ELE))  + wv*512 + l;
  const v8bf* Ew  = ((const v8bf*)(wsp + EXT_ELE)) + wv*512 + l;
  const v8bf* Wtp = ((const v8bf*)(wsp + WT_ELE))  + l;
  const v8bf* Wmp = ((const v8bf*)(wsp + WM_ELE))  + l;

  // bias folded into logit writes
  const float btv = (col < 4)  ? b_t[col] : 0.f;
  const float bmv = (col < 11) ? b_m[col] : 0.f;

  // PERSISTED loop-invariant B panels: ext table (8) + Whh kc=0 (8) = 64 VGPRs.
  // Re-read from L2 every phase before; now loaded once. Cuts ~22% of per-phase
  // L2 panel bytes and removes the ext-load latency at every half-start.
  v8bf ewr[8], bh0[8];
  #pragma unroll
  for (int nt=0;nt<8;++nt) { ewr[nt] = Ew[nt*64]; bh0[nt] = Bhh[nt*64]; }

  for (int i = t; i < RT*HS; i += NTHR) hA[i] = 0;

  float c_st[4][2][4];
  #pragma unroll
  for (int mt=0;mt<4;++mt)
    #pragma unroll
    for (int ub=0;ub<2;++ub)
      #pragma unroll
      for (int rg=0;rg<4;++rg) c_st[mt][ub][rg]=0.f;
  float lp = 0.f, entT = 0.f, entM = 0.f;
  int mask = 0xF;
  bool pend = false;            // pipelined softmax-m pending (runs after next B1)
  int pend_ma = 0;

  unsigned bpk[4][8][2];      // base = z@Wz^T packed as bf16 pairs (per branch), 64 VGPRs

  for (int br = 0; br < 2; ++br) {
    const float* z = br ? z2 : z1;
    // ---- branch head: stage z into hB (bf16 A-layout), ta, ma ----
    #pragma unroll
    for (int it = 0; it < 4; ++it) {
      int idx = t + it*NTHR;            // 0..2047 ; 64 rows x 32 chunks of 8 floats
      int r = idx>>5, c8 = idx&31;
      const float4 f0 = *(const float4*)&z[(r0+r)*256 + c8*8];
      const float4 f1 = *(const float4*)&z[(r0+r)*256 + c8*8 + 4];
      uint4 pk;
      pk.x = (unsigned)f32_to_bf16(f0.x) | ((unsigned)f32_to_bf16(f0.y)<<16);
      pk.y = (unsigned)f32_to_bf16(f0.z) | ((unsigned)f32_to_bf16(f0.w)<<16);
      pk.z = (unsigned)f32_to_bf16(f1.x) | ((unsigned)f32_to_bf16(f1.y)<<16);
      pk.w = (unsigned)f32_to_bf16(f1.z) | ((unsigned)f32_to_bf16(f1.w)<<16);
      *(uint4*)&hB[r*HS + c8*8] = pk;
    }
    if (t < 256)      { int e = t;     ta_l[(e&3)*RT + (e>>2)] = t_act[(r0+(e>>2))*8 + br*4 + (e&3)]; }
    else              { int e = t-256; ma_l[(e&3)*RT + (e>>2)] = m_act[(r0+(e>>2))*8 + br*4 + (e&3)]; }
    mask = 0xF;
    __syncthreads();
    if (t < RT) {                       // prev chain: all inputs (prev = ma of previous step)
      pa_l[t]        = (br==0) ? 15 : carry_l[t];
      pa_l[RT + t]   = ma_l[t];
      pa_l[2*RT + t] = ma_l[RT + t];
      pa_l[3*RT + t] = ma_l[2*RT + t];
      carry_l[t]     = ma_l[3*RT + t];
    }
    __syncthreads();
    // capture s=3 actions into registers (head-overwrite race closure)
    int ta3r = 0, ma3r = 0;
    if (t < RT) { ta3r = ta_l[3*RT + t]; ma3r = ma_l[3*RT + t]; }

    // ---- base = z @ Wz^T (A read from hB), per UB-half behind a backedge ----
    #pragma unroll 1
    for (int ub = 0; ub < 2; ++ub) {
      if (ub == 0) base_half<0>(bpk, Bz, hB, col, quad);
      else         base_half<1>(bpk, Bz, hB, col, quad);
    }
    __syncthreads();   // all waves done reading z from hB before P1(s=0) overwrites hB

    for (int s = 0; s < 4; ++s) {
      // ==== P1: LSTM1 (read hA -> write hB), two UB-halves behind a backedge ====
      #pragma unroll 1
      for (int ub = 0; ub < 2; ++ub) {
        if (ub == 0) lstm_half<0>(bpk, c_st, ewr, bh0, Bhh, &pa_l[s*RT], 16 + 2*br + 0, hA, hB, col, quad, wv);
        else         lstm_half<1>(bpk, c_st, ewr, bh0, Bhh, &pa_l[s*RT], 16 + 2*br + 0, hA, hB, col, quad, wv);
      }
      __syncthreads();                                   // B1: hB visible

      // ==== P4 (pipelined): softmax-m of PREVIOUS step, wave 0 ====
      if (pend && t < RT) softmax_m(ml_lds, t, pend_ma, lp, entM);
      pend = false;

      // ==== P2: LSTM2 (read hB -> write hA), two UB-halves, + t-logits (read hB) ====
      #pragma unroll 1
      for (int ub = 0; ub < 2; ++ub) {
        if (ub == 0) lstm_half<0>(bpk, c_st, ewr, bh0, Bhh, &ta_l[s*RT], 16 + 2*br + 1, hB, hA, col, quad, wv);
        else         lstm_half<1>(bpk, c_st, ewr, bh0, Bhh, &ta_l[s*RT], 16 + 2*br + 1, hB, hA, col, quad, wv);
      }
      if (wv < 4) {                                      // t-logits: wave wv -> rows wv*16..
        v4f lacc = (v4f){0.f,0.f,0.f,0.f};
        #pragma unroll
        for (int kc=0;kc<8;++kc) {
          v8bf A = *(const v8bf*)&hB[(wv*16+col)*HS + kc*32 + quad*8];
          lacc = MFMA(A, Wtp[kc*64], lacc, 0,0,0);
        }
        if (col < 4) {
          #pragma unroll
          for (int rg=0;rg<4;++rg) tl_lds[(wv*16 + quad*4 + rg)*4 + col] = lacc[rg] + btv;
        }
      }
      __syncthreads();                                   // B2: hA + tl visible

      // ==== P3: m-logits (waves 4-7, read hA) + softmax-t (wave 0). NO trailing barrier ====
      if (wv >= 4) {
        v4f lacc = (v4f){0.f,0.f,0.f,0.f};
        #pragma unroll
        for (int kc=0;kc<8;++kc) {
          v8bf A = *(const v8bf*)&hA[((wv-4)*16+col)*HS + kc*32 + quad*8];
          lacc = MFMA(A, Wmp[kc*64], lacc, 0,0,0);
        }
        if (col < 11) {
          #pragma unroll
          for (int rg=0;rg<4;++rg) ml_lds[((wv-4)*16 + quad*4 + rg)*12 + col] = lacc[rg] + bmv;
        }
      }
      if (t < RT) {
        int ta = (s==3) ? ta3r : ta_l[s*RT + t];
        float v[4];
        #pragma unroll
        for (int a=0;a<4;++a) {
          float raw = tl_lds[t*4+a];                     // bias already folded
          v[a] = ((mask>>a)&1) ? raw : -1e9f;
        }
        float mx = fmaxf(fmaxf(v[0],v[1]),fmaxf(v[2],v[3]));
        float se = 0.f;
        #pragma unroll
        for (int a=0;a<4;++a) se += __expf(v[a]-mx);
        float lse = mx + __logf(se);
        float sel = v[0];                                // static-index select chain
        #pragma unroll
        for (int a=1;a<4;++a) sel = (ta==a) ? v[a] : sel;
        lp += sel - lse;
        float e = 0.f;
        #pragma unroll
        for (int a=0;a<4;++a) { float l2 = v[a]-lse; e -= ((mask>>a)&1) ? __expf(l2)*l2 : 0.f; }
        entT += e;
        mask &= ~(1<<ta);
        pend_ma = (s==3) ? ma3r : ma_l[s*RT + t];        // register-carried for pipelined P4
      }
      pend = true;
    }
  }

  // flush last pending softmax-m (needs last P3's ml_lds visible)
  __syncthreads();
  if (pend && t < RT) softmax_m(ml_lds, t, pend_ma, lp, entM);

  // ---- outputs ----
  if (t < RT) {
    d_out[OUT_LP + r0 + t] = lp;
    float sT = entT, sM = entM;
    #pragma unroll
    for (int off=32; off; off>>=1) { sT += __shfl_down(sT, off, 64); sM += __shfl_down(sM, off, 64); }
    if (t == 0) {
      const float inv = 1.0f/524288.0f;                  // 1/(B*2S), exact 2^-19
      atomicAdd(d_out + OUT_TENT, sT*inv);
      atomicAdd(d_out + OUT_MENT, sM*inv);
    }
  }
  // passthrough copies: RT*8 = 512 elements each, one per thread
  d_out[OUT_TA + r0*8 + t] = (float)t_act[r0*8 + t];
  d_out[OUT_MA + r0*8 + t] = (float)m_act[r0*8 + t];
}

extern "C" void kernel_launch(void* const* d_in, const int* in_sizes, int n_in,
                              void* d_out, int out_size, void* d_ws, size_t ws_size,
                              hipStream_t stream) {
  const float* z1           = (const float*)d_in[0];
  const float* z2           = (const float*)d_in[1];
  const int*   t_act        = (const int*)d_in[2];
  const int*   m_act        = (const int*)d_in[3];
  const float* action_emb   = (const float*)d_in[4];
  const float* branch_emb   = (const float*)d_in[5];
  const float* actionid_emb = (const float*)d_in[6];
  const float* W_ih         = (const float*)d_in[7];
  const float* W_hh         = (const float*)d_in[8];
  const float* b_ih         = (const float*)d_in[9];
  const float* b_hh         = (const float*)d_in[10];
  const float* W_t          = (const float*)d_in[11];
  const float* b_t          = (const float*)d_in[12];
  const float* W_m          = (const float*)d_in[13];
  const float* b_m          = (const float*)d_in[14];
  float* out = (float*)d_out;
  unsigned short* wsp = (unsigned short*)d_ws;   // 565248 bf16 = 1.13MB

  precompute_kernel<<<(WS_ELE_TOTAL+255)/256, 256, 0, stream>>>(
      W_ih, W_hh, b_ih, b_hh, action_emb, branch_emb, actionid_emb, W_t, W_m, wsp, out);
  decoder_main<<<NBLK, NTHR, 0, stream>>>(z1, z2, t_act, m_act, b_t, b_m, wsp, out);
}

// Round 10
// 1558.387 us; speedup vs baseline: 1.9838x; 1.9838x over previous
//
#include <hip/hip_runtime.h>

#define BATCH 65536
#define RT 64              // rows per block
#define NBLK (BATCH/RT)    // 1024
#define NTHR 512           // 8 waves; wave w owns all 64 rows x (units w*32..w*32+31) x 4 gates
#define HS 264             // bf16 elems per LDS h row (256 + 8 pad)

typedef __bf16 v8bf __attribute__((ext_vector_type(8)));
typedef float  v4f  __attribute__((ext_vector_type(4)));
#define MFMA __builtin_amdgcn_mfma_f32_16x16x32_bf16

// ws layout, bf16-element offsets
// B packs: [kc 8][w 8][nt 8][lane 64][j 8]; nt = gate*2 + ub; col g = gate*256 + w*32 + ub*16 + (lane&15)
#define WHH_ELE 0
#define WZ_ELE  262144
#define EXT_ELE 524288     // [w 8][nt 8][lane 64][j 8], K=32 one-hot table (p=(lane>>4)*8+j)
#define WT_ELE  557056     // [kc 8][lane 64][j 8], N=16 (4 valid)
#define WM_ELE  561152     // [kc 8][lane 64][j 8], N=16 (11 valid)
#define WS_ELE_TOTAL 565248

// d_out layout (float offsets): log_p | t_actions | m_actions | t_ent | m_ent
#define OUT_LP 0
#define OUT_TA 65536
#define OUT_MA 589824
#define OUT_TENT 1114112
#define OUT_MENT 1114113

// v_rcp_f32 (~1 ulp) instead of IEEE div microcode (div_scale/div_fmas/div_fixup ~10 instr)
__device__ __forceinline__ float rcpf(float x){ return __builtin_amdgcn_rcpf(x); }
__device__ __forceinline__ float sigf(float x){ return rcpf(1.0f+__expf(-x)); }
__device__ __forceinline__ float tanhf_(float x){
  x = fminf(fmaxf(x, -15.0f), 15.0f);
  float e = __expf(2.0f*x);
  return 1.0f - 2.0f*rcpf(e+1.0f);   // == (e-1)/(e+1)
}
__device__ __forceinline__ unsigned short f32_to_bf16(float x){
  unsigned u = __float_as_uint(x);
  unsigned r = (u + 0x7fffu + ((u>>16)&1u)) >> 16;   // RNE
  return (unsigned short)r;
}

__global__ void precompute_kernel(const float* __restrict__ W_ih, const float* __restrict__ W_hh,
                                  const float* __restrict__ b_ih, const float* __restrict__ b_hh,
                                  const float* __restrict__ action_emb, const float* __restrict__ branch_emb,
                                  const float* __restrict__ actionid_emb,
                                  const float* __restrict__ W_t, const float* __restrict__ W_m,
                                  unsigned short* __restrict__ wsp, float* __restrict__ d_out) {
  int tid = blockIdx.x*256 + threadIdx.x;
  if (tid == 0) { d_out[OUT_TENT] = 0.f; d_out[OUT_MENT] = 0.f; }
  if (tid >= WS_ELE_TOTAL) return;
  float val = 0.f;
  if (tid < 524288) {                        // WHH / WZ packs
    int i = (tid < 262144) ? tid : tid - 262144;
    int j = i & 7, lane = (i>>3)&63, nt = (i>>9)&7, w = (i>>12)&7, kc = (i>>15)&7;
    int k = kc*32 + (lane>>4)*8 + j;
    int g = (nt>>1)*256 + w*32 + (nt&1)*16 + (lane&15);
    val = (tid < 262144) ? W_hh[g*256 + k] : W_ih[g*448 + k];
  } else if (tid < 557056) {                 // EXT one-hot table, K=32
    int i = tid - 524288;
    int j = i & 7, lane = (i>>3)&63, nt = (i>>9)&7, w = (i>>12)&7;
    int p = (lane>>4)*8 + j;
    int g = (nt>>1)*256 + w*32 + (nt&1)*16 + (lane&15);
    if (p < 16) {                            // action_emb[p] @ W_ih[:,384:448].T
      float s = 0.f;
      for (int e=0;e<64;++e) s += action_emb[p*64+e]*W_ih[g*448+384+e];
      val = s;
    } else if (p < 20) {                     // bias + branch + actionid, cidx = 16+2*br+aid
      int q = p-16, br = q>>1, aid = q&1;
      float s = b_ih[g] + b_hh[g];
      for (int e=0;e<64;++e)
        s += branch_emb[br*64+e]*W_ih[g*448+256+e] + actionid_emb[aid*64+e]*W_ih[g*448+320+e];
      val = s;
    }
  } else {                                   // WT / WM packs
    int base = (tid < 561152) ? 557056 : 561152;
    int i = tid - base;
    int j = i & 7, lane = (i>>3)&63, kc = (i>>9)&7;
    int k = kc*32 + (lane>>4)*8 + j;
    int a = lane & 15;
    if (tid < 561152) val = (a < 4)  ? W_t[a*256 + k] : 0.f;
    else              val = (a < 11) ? W_m[a*256 + k] : 0.f;
  }
  wsp[tid] = f32_to_bf16(val);
}

// HALF gemm: acc4[4][g] for gates g=0..3 at fixed ub; original B panel nt = g*2+ub.
// acc peak = 64 regs (vs 128 full) -> whole-kernel live set fits the 256-reg/wave
// budget (8-wave block => 2 waves/SIMD => 256 total), eliminating scratch spills.
__device__ __forceinline__ void run_gemm_h(v4f acc[4][4], const v8bf* __restrict__ Bw,
                                           const unsigned short* __restrict__ lds,
                                           int col, int quad, int ub) {
  #pragma unroll 2
  for (int kc = 0; kc < 8; ++kc) {
    v8bf A[4];
    #pragma unroll
    for (int mt=0;mt<4;++mt)
      A[mt] = *(const v8bf*)&lds[(mt*16+col)*HS + kc*32 + quad*8];
    #pragma unroll
    for (int g=0;g<4;++g) {
      v8bf B = Bw[kc*4096 + (g*2+ub)*64];
      #pragma unroll
      for (int mt=0;mt<4;++mt)
        acc[mt][g] = MFMA(A[mt], B, acc[mt][g], 0,0,0);
    }
  }
}

// one-hot K=32 chunk (half): per row adds EXT[idx_row] + EXT[cidx] into the ub-half gates
__device__ __forceinline__ void run_ext_h(v4f acc[4][4], const v8bf* __restrict__ Ew,
                                          const int* __restrict__ idx, int cidx,
                                          int col, int quad, int ub) {
  #pragma unroll
  for (int mt=0;mt<4;++mt) {
    int p0 = idx[mt*16 + col];
    v8bf oh;
    #pragma unroll
    for (int j=0;j<8;++j) { int k = quad*8+j; oh[j] = (k==p0 || k==cidx) ? (__bf16)1.0f : (__bf16)0.0f; }
    #pragma unroll
    for (int g=0;g<4;++g)
      acc[mt][g] = MFMA(oh, Ew[(g*2+ub)*64], acc[mt][g], 0,0,0);
  }
}

// softmax over 11 m-logits (bias pre-folded into ml_lds). All static indexing ->
// registers + cndmask select chain, no scratch (rule #20).
__device__ __forceinline__ void softmax_m(const float* __restrict__ ml, int t, int ma,
                                          float& lp, float& entM) {
  float mv[11];
  #pragma unroll
  for (int a=0;a<11;++a) mv[a] = ml[t*12+a];
  float mx = mv[0];
  #pragma unroll
  for (int a=1;a<11;++a) mx = fmaxf(mx, mv[a]);
  float se = 0.f;
  #pragma unroll
  for (int a=0;a<11;++a) se += __expf(mv[a]-mx);
  float lse = mx + __logf(se);
  float sel = mv[0];
  #pragma unroll
  for (int a=1;a<11;++a) sel = (ma==a) ? mv[a] : sel;
  lp += sel - lse;
  float e = 0.f;
  #pragma unroll
  for (int a=0;a<11;++a) { float l2 = mv[a]-lse; e -= __expf(l2)*l2; }
  entM += e;
}

__global__ __launch_bounds__(NTHR, 1) void decoder_main(
    const float* __restrict__ z1, const float* __restrict__ z2,
    const int* __restrict__ t_act, const int* __restrict__ m_act,
    const float* __restrict__ b_t, const float* __restrict__ b_m,
    const unsigned short* __restrict__ wsp, float* __restrict__ d_out) {
  // LDS: 2x33.8KB h buffers + ~7.3KB small = ~75.0KB. z staged INTO hB at branch head.
  __shared__ __align__(16) unsigned short hA[RT*HS];    // 33.8KB, [row][k] bf16
  __shared__ __align__(16) unsigned short hB[RT*HS];    // 33.8KB (double buffer; z staging at head)
  __shared__ float tl_lds[RT*4];
  __shared__ float ml_lds[RT*12];
  __shared__ int ta_l[4*RT], ma_l[4*RT], pa_l[4*RT], carry_l[RT];

  const int t = threadIdx.x, wv = t>>6, l = t&63, col = l&15, quad = l>>4;
  const int r0 = blockIdx.x * RT;
  const v8bf* Bhh = ((const v8bf*)(wsp + WHH_ELE)) + wv*512 + l;
  const v8bf* Bz  = ((const v8bf*)(wsp + WZ_ELE))  + wv*512 + l;
  const v8bf* Ew  = ((const v8bf*)(wsp + EXT_ELE)) + wv*512 + l;
  const v8bf* Wtp = ((const v8bf*)(wsp + WT_ELE))  + l;
  const v8bf* Wmp = ((const v8bf*)(wsp + WM_ELE))  + l;

  // bias folded into logit writes: 1 reg each, loaded once (keeps wave0 softmax off global)
  const float btv = (col < 4)  ? b_t[col] : 0.f;
  const float bmv = (col < 11) ? b_m[col] : 0.f;

  for (int i = t; i < RT*HS; i += NTHR) hA[i] = 0;

  float c_st[4][2][4];
  #pragma unroll
  for (int mt=0;mt<4;++mt)
    #pragma unroll
    for (int ub=0;ub<2;++ub)
      #pragma unroll
      for (int rg=0;rg<4;++rg) c_st[mt][ub][rg]=0.f;
  float lp = 0.f, entT = 0.f, entM = 0.f;
  int mask = 0xF;
  bool pend = false;            // pipelined softmax-m pending (runs after next B1)
  int pend_ma = 0;

  unsigned bpk[4][8][2];      // base = z@Wz^T packed as bf16 pairs (per branch), 64 VGPRs

  for (int br = 0; br < 2; ++br) {
    const float* z = br ? z2 : z1;
    // ---- branch head: stage z into hB (bf16 A-layout), ta, ma ----
    // hB is dead here: its last readers (P2 gemm + t-logits, s=3) completed before B2(s=3),
    // and every wave has passed B2 before reaching this staging loop.
    #pragma unroll
    for (int it = 0; it < 4; ++it) {
      int idx = t + it*NTHR;            // 0..2047 ; 64 rows x 32 chunks of 8 floats
      int r = idx>>5, c8 = idx&31;
      const float4 f0 = *(const float4*)&z[(r0+r)*256 + c8*8];
      const float4 f1 = *(const float4*)&z[(r0+r)*256 + c8*8 + 4];
      uint4 pk;
      pk.x = (unsigned)f32_to_bf16(f0.x) | ((unsigned)f32_to_bf16(f0.y)<<16);
      pk.y = (unsigned)f32_to_bf16(f0.z) | ((unsigned)f32_to_bf16(f0.w)<<16);
      pk.z = (unsigned)f32_to_bf16(f1.x) | ((unsigned)f32_to_bf16(f1.y)<<16);
      pk.w = (unsigned)f32_to_bf16(f1.z) | ((unsigned)f32_to_bf16(f1.w)<<16);
      *(uint4*)&hB[r*HS + c8*8] = pk;
    }
    if (t < 256)      { int e = t;     ta_l[(e&3)*RT + (e>>2)] = t_act[(r0+(e>>2))*8 + br*4 + (e&3)]; }
    else              { int e = t-256; ma_l[(e&3)*RT + (e>>2)] = m_act[(r0+(e>>2))*8 + br*4 + (e&3)]; }
    mask = 0xF;
    __syncthreads();
    if (t < RT) {                       // prev chain: all inputs (prev = ma of previous step)
      pa_l[t]        = (br==0) ? 15 : carry_l[t];
      pa_l[RT + t]   = ma_l[t];
      pa_l[2*RT + t] = ma_l[RT + t];
      pa_l[3*RT + t] = ma_l[2*RT + t];
      carry_l[t]     = ma_l[3*RT + t];
    }
    __syncthreads();
    // capture s=3 actions into registers: closes the head-overwrite race on wave0's
    // last-step softmax reads (next branch's staging rewrites ta_l/ma_l with no
    // barrier between P3(s=3) and the head).
    int ta3r = 0, ma3r = 0;
    if (t < RT) { ta3r = ta_l[3*RT + t]; ma3r = ma_l[3*RT + t]; }

    // ---- base = z @ Wz^T (A read from hB), per ub-half, packed bf16 into bpk ----
    #pragma unroll 1
    for (int ub = 0; ub < 2; ++ub) {
      v4f acc[4][4];
      #pragma unroll
      for (int mt=0;mt<4;++mt)
        #pragma unroll
        for (int g=0;g<4;++g) acc[mt][g] = (v4f){0.f,0.f,0.f,0.f};
      run_gemm_h(acc, Bz, hB, col, quad, ub);
      #pragma unroll
      for (int mt=0;mt<4;++mt)
        #pragma unroll
        for (int g=0;g<4;++g) {
          bpk[mt][g*2+ub][0] = (unsigned)f32_to_bf16(acc[mt][g][0]) | ((unsigned)f32_to_bf16(acc[mt][g][1])<<16);
          bpk[mt][g*2+ub][1] = (unsigned)f32_to_bf16(acc[mt][g][2]) | ((unsigned)f32_to_bf16(acc[mt][g][3])<<16);
        }
    }
    __syncthreads();   // all waves done reading z from hB before P1(s=0) overwrites hB

    for (int s = 0; s < 4; ++s) {
      // ==== P1: LSTM1 (read hA -> write hB), two ub-halves ====
      #pragma unroll 1
      for (int ub = 0; ub < 2; ++ub) {
        v4f acc[4][4];
        #pragma unroll
        for (int mt=0;mt<4;++mt)
          #pragma unroll
          for (int g=0;g<4;++g) {
            unsigned p0 = bpk[mt][g*2+ub][0], p1 = bpk[mt][g*2+ub][1];
            acc[mt][g] = (v4f){ __uint_as_float(p0<<16), __uint_as_float(p0 & 0xffff0000u),
                                __uint_as_float(p1<<16), __uint_as_float(p1 & 0xffff0000u) };
          }
        run_ext_h(acc, Ew, &pa_l[s*RT], 16 + 2*br + 0, col, quad, ub);
        run_gemm_h(acc, Bhh, hA, col, quad, ub);
        #pragma unroll
        for (int mt=0;mt<4;++mt)
          #pragma unroll
          for (int rg=0;rg<4;++rg) {
            float gi = sigf(acc[mt][0][rg]);
            float gf = sigf(acc[mt][1][rg]);
            float gg = tanhf_(acc[mt][2][rg]);
            float go = sigf(acc[mt][3][rg]);
            float cn = gf*c_st[mt][ub][rg] + gi*gg;
            c_st[mt][ub][rg] = cn;
            hB[(mt*16 + quad*4 + rg)*HS + wv*32 + ub*16 + col] = f32_to_bf16(go*tanhf_(cn));
          }
      }
      __syncthreads();                                   // B1: hB visible

      // ==== P4 (pipelined): softmax-m of PREVIOUS step, wave 0 ====
      // ml_lds from last P3 is stable between B1 and B2 (next write is post-B2).
      if (pend && t < RT) softmax_m(ml_lds, t, pend_ma, lp, entM);
      pend = false;

      // ==== P2: LSTM2 (read hB -> write hA), two ub-halves, + t-logits (read hB) ====
      #pragma unroll 1
      for (int ub = 0; ub < 2; ++ub) {
        v4f acc[4][4];
        #pragma unroll
        for (int mt=0;mt<4;++mt)
          #pragma unroll
          for (int g=0;g<4;++g) {
            unsigned p0 = bpk[mt][g*2+ub][0], p1 = bpk[mt][g*2+ub][1];
            acc[mt][g] = (v4f){ __uint_as_float(p0<<16), __uint_as_float(p0 & 0xffff0000u),
                                __uint_as_float(p1<<16), __uint_as_float(p1 & 0xffff0000u) };
          }
        run_ext_h(acc, Ew, &ta_l[s*RT], 16 + 2*br + 1, col, quad, ub);
        run_gemm_h(acc, Bhh, hB, col, quad, ub);
        #pragma unroll
        for (int mt=0;mt<4;++mt)
          #pragma unroll
          for (int rg=0;rg<4;++rg) {
            float gi = sigf(acc[mt][0][rg]);
            float gf = sigf(acc[mt][1][rg]);
            float gg = tanhf_(acc[mt][2][rg]);
            float go = sigf(acc[mt][3][rg]);
            float cn = gf*c_st[mt][ub][rg] + gi*gg;
            c_st[mt][ub][rg] = cn;
            hA[(mt*16 + quad*4 + rg)*HS + wv*32 + ub*16 + col] = f32_to_bf16(go*tanhf_(cn));
          }
      }
      if (wv < 4) {                                      // t-logits: wave wv -> rows wv*16..
        v4f lacc = (v4f){0.f,0.f,0.f,0.f};
        #pragma unroll
        for (int kc=0;kc<8;++kc) {
          v8bf A = *(const v8bf*)&hB[(wv*16+col)*HS + kc*32 + quad*8];
          lacc = MFMA(A, Wtp[kc*64], lacc, 0,0,0);
        }
        if (col < 4) {
          #pragma unroll
          for (int rg=0;rg<4;++rg) tl_lds[(wv*16 + quad*4 + rg)*4 + col] = lacc[rg] + btv;
        }
      }
      __syncthreads();                                   // B2: hA + tl visible

      // ==== P3: m-logits (waves 4-7, read hA) + softmax-t (wave 0). NO trailing barrier:
      // all waves fall straight into P1(s+1) (reads hA/writes hB: both safe post-B2).
      if (wv >= 4) {
        v4f lacc = (v4f){0.f,0.f,0.f,0.f};
        #pragma unroll
        for (int kc=0;kc<8;++kc) {
          v8bf A = *(const v8bf*)&hA[((wv-4)*16+col)*HS + kc*32 + quad*8];
          lacc = MFMA(A, Wmp[kc*64], lacc, 0,0,0);
        }
        if (col < 11) {
          #pragma unroll
          for (int rg=0;rg<4;++rg) ml_lds[((wv-4)*16 + quad*4 + rg)*12 + col] = lacc[rg] + bmv;
        }
      }
      if (t < RT) {
        int ta = (s==3) ? ta3r : ta_l[s*RT + t];
        float v[4];
        #pragma unroll
        for (int a=0;a<4;++a) {
          float raw = tl_lds[t*4+a];                     // bias already folded
          v[a] = ((mask>>a)&1) ? raw : -1e9f;
        }
        float mx = fmaxf(fmaxf(v[0],v[1]),fmaxf(v[2],v[3]));
        float se = 0.f;
        #pragma unroll
        for (int a=0;a<4;++a) se += __expf(v[a]-mx);
        float lse = mx + __logf(se);
        float sel = v[0];                                // static-index select chain, no scratch
        #pragma unroll
        for (int a=1;a<4;++a) sel = (ta==a) ? v[a] : sel;
        lp += sel - lse;
        float e = 0.f;
        #pragma unroll
        for (int a=0;a<4;++a) { float l2 = v[a]-lse; e -= ((mask>>a)&1) ? __expf(l2)*l2 : 0.f; }
        entT += e;
        mask &= ~(1<<ta);
        pend_ma = (s==3) ? ma3r : ma_l[s*RT + t];        // register-carried for pipelined P4
      }
      pend = true;
    }
  }

  // flush last pending softmax-m (needs last P3's ml_lds visible)
  __syncthreads();
  if (pend && t < RT) softmax_m(ml_lds, t, pend_ma, lp, entM);

  // ---- outputs ----
  if (t < RT) {
    d_out[OUT_LP + r0 + t] = lp;
    float sT = entT, sM = entM;
    #pragma unroll
    for (int off=32; off; off>>=1) { sT += __shfl_down(sT, off, 64); sM += __shfl_down(sM, off, 64); }
    if (t == 0) {
      const float inv = 1.0f/524288.0f;                  // 1/(B*2S), exact 2^-19
      atomicAdd(d_out + OUT_TENT, sT*inv);
      atomicAdd(d_out + OUT_MENT, sM*inv);
    }
  }
  // passthrough copies: RT*8 = 512 elements each, one per thread
  d_out[OUT_TA + r0*8 + t] = (float)t_act[r0*8 + t];
  d_out[OUT_MA + r0*8 + t] = (float)m_act[r0*8 + t];
}

extern "C" void kernel_launch(void* const* d_in, const int* in_sizes, int n_in,
                              void* d_out, int out_size, void* d_ws, size_t ws_size,
                              hipStream_t stream) {
  const float* z1           = (const float*)d_in[0];
  const float* z2           = (const float*)d_in[1];
  const int*   t_act        = (const int*)d_in[2];
  const int*   m_act        = (const int*)d_in[3];
  const float* action_emb   = (const float*)d_in[4];
  const float* branch_emb   = (const float*)d_in[5];
  const float* actionid_emb = (const float*)d_in[6];
  const float* W_ih         = (const float*)d_in[7];
  const float* W_hh         = (const float*)d_in[8];
  const float* b_ih         = (const float*)d_in[9];
  const float* b_hh         = (const float*)d_in[10];
  const float* W_t          = (const float*)d_in[11];
  const float* b_t          = (const float*)d_in[12];
  const float* W_m          = (const float*)d_in[13];
  const float* b_m          = (const float*)d_in[14];
  float* out = (float*)d_out;
  unsigned short* wsp = (unsigned short*)d_ws;   // 565248 bf16 = 1.13MB

  precompute_kernel<<<(WS_ELE_TOTAL+255)/256, 256, 0, stream>>>(
      W_ih, W_hh, b_ih, b_hh, action_emb, branch_emb, actionid_emb, W_t, W_m, wsp, out);
  decoder_main<<<NBLK, NTHR, 0, stream>>>(z1, z2, t_act, m_act, b_t, b_m, wsp, out);
}